// Round 2
// baseline (47735.394 us; speedup 1.0000x reference)
//
#include <hip/hip_runtime.h>

#define B_SZ    64
#define T_STEPS 512
#define U1      128
#define S1      128
#define U2      256
#define S2      128
#define NUNF    6

__device__ __forceinline__ float fast_exp2(float x) { return __builtin_amdgcn_exp2f(x); }
__device__ __forceinline__ float fast_rcp(float x)  { return __builtin_amdgcn_rcpf(x); }

// ---------------------------------------------------------------------------
// Param transform (SoA): A = sigma*log2(e), B = mu*sigma*log2(e), W = w*erev
// sigmoid((v-mu)*sigma) = 1 / (1 + exp2(B - A*v));  |W| = w*mask (w > 0).
// ---------------------------------------------------------------------------
__global__ void prep_soa(const float* __restrict__ sigma, const float* __restrict__ mu,
                         const float* __restrict__ w, const float* __restrict__ erev,
                         float* __restrict__ A, float* __restrict__ Bb,
                         float* __restrict__ W, int n)
{
    int i = blockIdx.x * 256 + threadIdx.x;
    if (i >= n) return;
    const float L2E = 1.4426950408889634f;
    float a = sigma[i] * L2E;
    A[i] = a; Bb[i] = mu[i] * a; W[i] = w[i] * erev[i];
}

__global__ void prep_vec(const float* __restrict__ gleak, const float* __restrict__ vleak,
                         const float* __restrict__ cm,
                         float* __restrict__ cmt, float* __restrict__ nb,
                         float* __restrict__ db, int n)
{
    int i = blockIdx.x * 256 + threadIdx.x;
    if (i >= n) return;
    float c6 = cm[i] * 6.f;
    float gl = gleak[i];
    cmt[i] = c6;
    nb[i]  = gl * vleak[i];
    db[i]  = c6 + gl + 1e-8f;
}

// ---------------------------------------------------------------------------
// Layer 1: S=128, U=128. 512 threads: uo=tid&127, g=tid>>7 (4 groups x 32 s).
// ALL params (32 sensory + 32 recurrent pairs/thread) cached in registers.
// ---------------------------------------------------------------------------
__global__ __launch_bounds__(512, 1) void ltc1(
    const float* __restrict__ x,
    const float* __restrict__ in_w, const float* __restrict__ in_b,
    const float* __restrict__ As, const float* __restrict__ Bs, const float* __restrict__ Ws,
    const float* __restrict__ Ar, const float* __restrict__ Br, const float* __restrict__ Wr,
    const float* __restrict__ cmt, const float* __restrict__ nbv, const float* __restrict__ dbv,
    const float* __restrict__ ow, const float* __restrict__ ob,
    float* __restrict__ h1)
{
    const int b   = blockIdx.x;
    const int tid = threadIdx.x;
    const int uo  = tid & (U1 - 1);
    const int g   = tid >> 7;

    __shared__ float  v[U1];
    __shared__ float  ibuf[S1];
    __shared__ float2 red[4][U1];
    __shared__ float  nbs[U1], dbs[U1];

    float sA[32], sB[32], sW[32], rA[32], rB[32], rW[32];
    #pragma unroll
    for (int j = 0; j < 32; ++j) {
        int idx = (g * 32 + j) * U1 + uo;
        sA[j] = As[idx]; sB[j] = Bs[idx]; sW[j] = Ws[idx];
        rA[j] = Ar[idx]; rB[j] = Br[idx]; rW[j] = Wr[idx];
    }

    float c_cmt = 0, c_nb = 0, c_db = 0, c_iw = 0, c_ib = 0, c_ow = 0, c_ob = 0;
    if (tid < U1) {
        v[tid] = 0.f;
        c_cmt = cmt[tid]; c_nb = nbv[tid]; c_db = dbv[tid];
        c_iw = in_w[tid]; c_ib = in_b[tid];
        c_ow = ow[tid];   c_ob = ob[tid];
    }
    const float* xb = x  + (size_t)b * T_STEPS * S1;
    float*       hb = h1 + (size_t)b * T_STEPS * U1;

    for (int t = 0; t < T_STEPS; ++t) {
        if (tid < S1) ibuf[tid] = fmaf(xb[t * S1 + tid], c_iw, c_ib);
        __syncthreads();

        // sensory partials
        {
            float an = 0.f, ad = 0.f;
            #pragma unroll
            for (int jj = 0; jj < 8; ++jj) {
                float4 iv = *reinterpret_cast<const float4*>(&ibuf[g * 32 + jj * 4]);
                float vals[4] = {iv.x, iv.y, iv.z, iv.w};
                #pragma unroll
                for (int q = 0; q < 4; ++q) {
                    int j = jj * 4 + q;
                    float e = fast_exp2(sB[j] - sA[j] * vals[q]);
                    float r = fast_rcp(1.f + e);
                    an = fmaf(sW[j], r, an);
                    ad = fmaf(fabsf(sW[j]), r, ad);
                }
            }
            red[g][uo] = make_float2(an, ad);
        }
        __syncthreads();
        if (tid < U1) {
            float2 r0 = red[0][tid], r1 = red[1][tid], r2 = red[2][tid], r3 = red[3][tid];
            nbs[tid] = c_nb + ((r0.x + r1.x) + (r2.x + r3.x));
            dbs[tid] = c_db + ((r0.y + r1.y) + (r2.y + r3.y));
        }
        __syncthreads();

        for (int k = 0; k < NUNF; ++k) {
            float an = 0.f, ad = 0.f;
            #pragma unroll
            for (int jj = 0; jj < 8; ++jj) {
                float4 vv = *reinterpret_cast<const float4*>(&v[g * 32 + jj * 4]);
                float vals[4] = {vv.x, vv.y, vv.z, vv.w};
                #pragma unroll
                for (int q = 0; q < 4; ++q) {
                    int j = jj * 4 + q;
                    float e = fast_exp2(rB[j] - rA[j] * vals[q]);
                    float r = fast_rcp(1.f + e);
                    an = fmaf(rW[j], r, an);
                    ad = fmaf(fabsf(rW[j]), r, ad);
                }
            }
            red[g][uo] = make_float2(an, ad);
            __syncthreads();
            if (tid < U1) {
                float2 r0 = red[0][tid], r1 = red[1][tid], r2 = red[2][tid], r3 = red[3][tid];
                float wn = nbs[tid] + ((r0.x + r1.x) + (r2.x + r3.x));
                float wd = dbs[tid] + ((r0.y + r1.y) + (r2.y + r3.y));
                v[tid] = fmaf(c_cmt, v[tid], wn) * fast_rcp(wd);
            }
            __syncthreads();
        }
        if (tid < U1) hb[t * U1 + tid] = fmaf(v[tid], c_ow, c_ob);
    }
}

// ---------------------------------------------------------------------------
// Layer 2: S=128, U=256. 512 threads: uo=tid&255, g=tid>>8 (2 groups x 128 s).
// 64 of 128 recurrent pairs/thread register-cached; rest + sensory streamed SoA.
// Writes h2 (motor-mapped) to workspace; FC head is a separate kernel.
// ---------------------------------------------------------------------------
__global__ __launch_bounds__(512, 1) void ltc2(
    const float* __restrict__ h1,
    const float* __restrict__ in_w, const float* __restrict__ in_b,
    const float* __restrict__ As, const float* __restrict__ Bs, const float* __restrict__ Ws,
    const float* __restrict__ Ar, const float* __restrict__ Br, const float* __restrict__ Wr,
    const float* __restrict__ cmt, const float* __restrict__ nbv, const float* __restrict__ dbv,
    const float* __restrict__ ow, const float* __restrict__ ob,
    float* __restrict__ h2)                      // [64][512][64]
{
    const int b   = blockIdx.x;
    const int tid = threadIdx.x;
    const int uo  = tid & (U2 - 1);
    const int g   = tid >> 8;

    __shared__ float  v[U2];
    __shared__ float  ibuf[S2];
    __shared__ float2 red[2][U2];
    __shared__ float  nbs[U2], dbs[U2];

    // register-cache first 64 recurrent pairs of this thread's 128
    float rA[64], rB[64], rW[64];
    #pragma unroll
    for (int j = 0; j < 64; ++j) {
        int idx = (g * 128 + j) * U2 + uo;
        rA[j] = Ar[idx]; rB[j] = Br[idx]; rW[j] = Wr[idx];
    }

    float c_cmt = 0, c_nb = 0, c_db = 0;
    if (tid < U2) {
        v[tid] = 0.f;
        c_cmt = cmt[tid]; c_nb = nbv[tid]; c_db = dbv[tid];
    }
    float c_iw = 0, c_ib = 0;
    if (tid < S2) { c_iw = in_w[tid]; c_ib = in_b[tid]; }
    float c_ow = 0, c_ob = 0;
    if (tid < 64) { c_ow = ow[tid]; c_ob = ob[tid]; }

    const float* hb = h1 + (size_t)b * T_STEPS * S2;
    float*       op = h2 + (size_t)b * T_STEPS * 64;

    const float* pAs = As + (size_t)(g * 64) * U2 + uo;
    const float* pBs = Bs + (size_t)(g * 64) * U2 + uo;
    const float* pWs = Ws + (size_t)(g * 64) * U2 + uo;
    const float* pAr = Ar + (size_t)(g * 128 + 64) * U2 + uo;
    const float* pBr = Br + (size_t)(g * 128 + 64) * U2 + uo;
    const float* pWr = Wr + (size_t)(g * 128 + 64) * U2 + uo;

    for (int t = 0; t < T_STEPS; ++t) {
        if (tid < S2) ibuf[tid] = fmaf(hb[t * S2 + tid], c_iw, c_ib);
        __syncthreads();

        // sensory partials (64 streamed pairs, s = g*64 + j)
        {
            float an = 0.f, ad = 0.f;
            #pragma unroll 4
            for (int j = 0; j < 64; ++j) {
                float a = pAs[(size_t)j * U2];
                float bb = pBs[(size_t)j * U2];
                float w = pWs[(size_t)j * U2];
                float iv = ibuf[g * 64 + j];
                float e = fast_exp2(bb - a * iv);
                float r = fast_rcp(1.f + e);
                an = fmaf(w, r, an);
                ad = fmaf(fabsf(w), r, ad);
            }
            red[g][uo] = make_float2(an, ad);
        }
        __syncthreads();
        if (tid < U2) {
            float2 r0 = red[0][tid], r1 = red[1][tid];
            nbs[tid] = c_nb + r0.x + r1.x;
            dbs[tid] = c_db + r0.y + r1.y;
        }
        __syncthreads();

        for (int k = 0; k < NUNF; ++k) {
            float an = 0.f, ad = 0.f;
            // cached 64 pairs (s = g*128 + j)
            #pragma unroll
            for (int jj = 0; jj < 16; ++jj) {
                float4 vv = *reinterpret_cast<const float4*>(&v[g * 128 + jj * 4]);
                float vals[4] = {vv.x, vv.y, vv.z, vv.w};
                #pragma unroll
                for (int q = 0; q < 4; ++q) {
                    int j = jj * 4 + q;
                    float e = fast_exp2(rB[j] - rA[j] * vals[q]);
                    float r = fast_rcp(1.f + e);
                    an = fmaf(rW[j], r, an);
                    ad = fmaf(fabsf(rW[j]), r, ad);
                }
            }
            // streamed 64 pairs (s = g*128 + 64 + j)
            #pragma unroll 4
            for (int j = 0; j < 64; ++j) {
                float a = pAr[(size_t)j * U2];
                float bb = pBr[(size_t)j * U2];
                float w = pWr[(size_t)j * U2];
                float vj = v[g * 128 + 64 + j];
                float e = fast_exp2(bb - a * vj);
                float r = fast_rcp(1.f + e);
                an = fmaf(w, r, an);
                ad = fmaf(fabsf(w), r, ad);
            }
            red[g][uo] = make_float2(an, ad);
            __syncthreads();
            if (tid < U2) {
                float2 r0 = red[0][tid], r1 = red[1][tid];
                float wn = nbs[tid] + r0.x + r1.x;
                float wd = dbs[tid] + r0.y + r1.y;
                v[tid] = fmaf(c_cmt, v[tid], wn) * fast_rcp(wd);
            }
            __syncthreads();
        }
        if (tid < 64) op[t * 64 + tid] = fmaf(v[tid], c_ow, c_ob);
    }
}

// ---------------------------------------------------------------------------
// FC head: out[b,t,o] = fcb[o] + sum_k h2[b,t,k] * fcw[o,k]
// block = 512 threads = 8 timesteps x 64 outputs; grid = B*T/8
// ---------------------------------------------------------------------------
__global__ __launch_bounds__(512, 1) void fc_head(
    const float* __restrict__ h2, const float* __restrict__ fcw,
    const float* __restrict__ fcb, float* __restrict__ out)
{
    __shared__ float fwT[64 * 64];
    __shared__ float hs[8 * 64];
    const int tid = threadIdx.x;
    for (int i = tid; i < 64 * 64; i += 512) {
        int o = i >> 6, k = i & 63;
        fwT[k * 64 + o] = fcw[i];
    }
    size_t base = (size_t)blockIdx.x * 8 * 64;
    hs[tid] = h2[base + tid];
    __syncthreads();
    const int o = tid & 63, tt = tid >> 6;
    float acc = fcb[o];
    #pragma unroll
    for (int k = 0; k < 64; ++k)
        acc = fmaf(hs[tt * 64 + k], fwT[k * 64 + o], acc);
    out[base + tt * 64 + o] = acc;
}

// ---------------------------------------------------------------------------
extern "C" void kernel_launch(void* const* d_in, const int* in_sizes, int n_in,
                              void* d_out, int out_size, void* d_ws, size_t ws_size,
                              hipStream_t stream)
{
    (void)in_sizes; (void)n_in; (void)out_size; (void)ws_size;

    const float* x      = (const float*)d_in[0];
    const float* l1_iw  = (const float*)d_in[1];
    const float* l1_ib  = (const float*)d_in[2];
    const float* l1_sw  = (const float*)d_in[3];
    const float* l1_ss  = (const float*)d_in[4];
    const float* l1_smu = (const float*)d_in[5];
    const float* l1_se  = (const float*)d_in[6];
    const float* l1_w   = (const float*)d_in[8];
    const float* l1_sg  = (const float*)d_in[9];
    const float* l1_mu  = (const float*)d_in[10];
    const float* l1_er  = (const float*)d_in[11];
    const float* l1_gl  = (const float*)d_in[13];
    const float* l1_vl  = (const float*)d_in[14];
    const float* l1_cm  = (const float*)d_in[15];
    const float* l1_ow  = (const float*)d_in[16];
    const float* l1_ob  = (const float*)d_in[17];
    const float* l2_iw  = (const float*)d_in[18];
    const float* l2_ib  = (const float*)d_in[19];
    const float* l2_sw  = (const float*)d_in[20];
    const float* l2_ss  = (const float*)d_in[21];
    const float* l2_smu = (const float*)d_in[22];
    const float* l2_se  = (const float*)d_in[23];
    const float* l2_w   = (const float*)d_in[25];
    const float* l2_sg  = (const float*)d_in[26];
    const float* l2_mu  = (const float*)d_in[27];
    const float* l2_er  = (const float*)d_in[28];
    const float* l2_gl  = (const float*)d_in[30];
    const float* l2_vl  = (const float*)d_in[31];
    const float* l2_cm  = (const float*)d_in[32];
    const float* l2_ow  = (const float*)d_in[33];
    const float* l2_ob  = (const float*)d_in[34];
    const float* fcw    = (const float*)d_in[35];
    const float* fcb    = (const float*)d_in[36];

    float* W = (float*)d_ws;
    size_t off = 0;
    float* h1 = W + off; off += (size_t)B_SZ * T_STEPS * U1;
    float* h2 = W + off; off += (size_t)B_SZ * T_STEPS * 64;
    float* A1s = W + off; off += S1 * U1;  float* B1s = W + off; off += S1 * U1;  float* W1s = W + off; off += S1 * U1;
    float* A1r = W + off; off += U1 * U1;  float* B1r = W + off; off += U1 * U1;  float* W1r = W + off; off += U1 * U1;
    float* A2s = W + off; off += S2 * U2;  float* B2s = W + off; off += S2 * U2;  float* W2s = W + off; off += S2 * U2;
    float* A2r = W + off; off += U2 * U2;  float* B2r = W + off; off += U2 * U2;  float* W2r = W + off; off += U2 * U2;
    float* cmt1 = W + off; off += U1;
    float* nb1  = W + off; off += U1;
    float* db1  = W + off; off += U1;
    float* cmt2 = W + off; off += U2;
    float* nb2  = W + off; off += U2;
    float* db2  = W + off; off += U2;

    prep_soa<<<(S1 * U1 + 255) / 256, 256, 0, stream>>>(l1_ss, l1_smu, l1_sw, l1_se, A1s, B1s, W1s, S1 * U1);
    prep_soa<<<(U1 * U1 + 255) / 256, 256, 0, stream>>>(l1_sg, l1_mu,  l1_w,  l1_er, A1r, B1r, W1r, U1 * U1);
    prep_soa<<<(S2 * U2 + 255) / 256, 256, 0, stream>>>(l2_ss, l2_smu, l2_sw, l2_se, A2s, B2s, W2s, S2 * U2);
    prep_soa<<<(U2 * U2 + 255) / 256, 256, 0, stream>>>(l2_sg, l2_mu,  l2_w,  l2_er, A2r, B2r, W2r, U2 * U2);
    prep_vec<<<1, 256, 0, stream>>>(l1_gl, l1_vl, l1_cm, cmt1, nb1, db1, U1);
    prep_vec<<<1, 256, 0, stream>>>(l2_gl, l2_vl, l2_cm, cmt2, nb2, db2, U2);

    ltc1<<<B_SZ, 512, 0, stream>>>(x, l1_iw, l1_ib, A1s, B1s, W1s, A1r, B1r, W1r,
                                   cmt1, nb1, db1, l1_ow, l1_ob, h1);
    ltc2<<<B_SZ, 512, 0, stream>>>(h1, l2_iw, l2_ib, A2s, B2s, W2s, A2r, B2r, W2r,
                                   cmt2, nb2, db2, l2_ow, l2_ob, h2);
    fc_head<<<B_SZ * T_STEPS / 8, 512, 0, stream>>>(h2, fcw, fcb, (float*)d_out);
}